// Round 6
// baseline (212.281 us; speedup 1.0000x reference)
//
#include <hip/hip_runtime.h>

#define SL  2048
#define BSZ 32
#define DIM 1024
#define NH  16
#define HD  64

typedef __attribute__((ext_vector_type(4))) float f32x4;
typedef __attribute__((ext_vector_type(8))) short s16x8;

static __device__ __forceinline__ short f2bf(float f) {
    union { float f; unsigned u; } v; v.f = f;
    unsigned r = (v.u + 0x7fffu + ((v.u >> 16) & 1u)) >> 16;  // RNE
    return (short)r;
}

// Fused: qp_slice[i] = query[b].Wq[h*64+i] (i<64), then
// u[b][h][j] = 0.125 * sum_i qp_slice[i] * Wk[h*64+i][j]  (bf16)
__global__ __launch_bounds__(256) void k_qu(const float* __restrict__ query,
                                            const float* __restrict__ Wq,
                                            const float* __restrict__ Wk,
                                            short* __restrict__ u) {
    int b = blockIdx.x & 31;
    int h = blockIdx.x >> 5;
    int t = threadIdx.x;
    __shared__ float red[256];
    __shared__ float sq[HD];
    {
        int i  = t >> 2;
        int kq = t & 3;
        const float* q = query + (size_t)b * DIM + kq * 256;
        const float* w = Wq + (size_t)(h * HD + i) * DIM + kq * 256;
        f32x4 acc = {0.f, 0.f, 0.f, 0.f};
#pragma unroll 4
        for (int k = 0; k < 256; k += 4)
            acc += *(const f32x4*)(q + k) * *(const f32x4*)(w + k);
        red[t] = acc[0] + acc[1] + acc[2] + acc[3];
    }
    __syncthreads();
    if (t < HD) sq[t] = (red[t*4] + red[t*4+1] + red[t*4+2] + red[t*4+3]) * 0.125f;
    __syncthreads();
    f32x4 acc = {0.f, 0.f, 0.f, 0.f};
    const float* wk = Wk + (size_t)(h * HD) * DIM;
#pragma unroll 8
    for (int i = 0; i < HD; ++i) {
        float s = sq[i];
        const float* row = wk + (size_t)i * DIM;
        acc[0] += s * row[t];
        acc[1] += s * row[t + 256];
        acc[2] += s * row[t + 512];
        acc[3] += s * row[t + 768];
    }
    short* ub = u + ((size_t)(b * NH + h)) * DIM;
    ub[t]       = f2bf(acc[0]);
    ub[t + 256] = f2bf(acc[1]);
    ub[t + 512] = f2bf(acc[2]);
    ub[t + 768] = f2bf(acc[3]);
}

// dot[b][s][h] = keys[s,b,:].u[b,h,:]  via LDS-staged keys (contiguous 1KB reads).
// grid 4096 = 128 st x 32 b (b fastest); block 256 = 4 waves, each wave a K-quarter.
__global__ __launch_bounds__(256) void k_dot2(const float* __restrict__ keys,
                                              const short* __restrict__ u,
                                              float* __restrict__ dot,
                                              float2* __restrict__ part) {
    int b  = blockIdx.x & 31;
    int st = blockIdx.x >> 5;          // 0..127
    int s0 = st * 16;
    __shared__ short ulds[NH][DIM + 8];
    __shared__ short klds[16][DIM + 8];
    __shared__ f32x4 redc[4][64];
    int t = threadIdx.x;
    int w = t >> 6, l = t & 63;

    // stage u (bf16, L2-hot)
    {
        const uint4* src = (const uint4*)(u + (size_t)b * NH * DIM);
        for (int idx = t; idx < NH * DIM / 8; idx += 256) {
            int row = idx >> 7;
            int col = (idx & 127) * 8;
            *(uint4*)&ulds[row][col] = src[idx];
        }
    }
    // stage keys -> bf16; each wave 4 rows, lane-k-major: 1KB contiguous per instr
#pragma unroll
    for (int r = 0; r < 4; ++r) {
        int srow = w * 4 + r;
        const float* kr = keys + ((size_t)(s0 + srow) * BSZ + b) * DIM;
#pragma unroll
        for (int kq = 0; kq < 4; ++kq) {
            f32x4 v = *(const f32x4*)(kr + kq * 256 + l * 4);
            ushort4 o;
            o.x = (unsigned short)f2bf(v[0]);
            o.y = (unsigned short)f2bf(v[1]);
            o.z = (unsigned short)f2bf(v[2]);
            o.w = (unsigned short)f2bf(v[3]);
            *(ushort4*)&klds[srow][kq * 256 + l * 4] = o;
        }
    }
    __syncthreads();

    int lrow = l & 15, kgrp = l >> 4;
    f32x4 acc = {0.f, 0.f, 0.f, 0.f};
#pragma unroll
    for (int kk = 0; kk < 8; ++kk) {
        int kj = w * 256 + kk * 32 + kgrp * 8;
        s16x8 af = *(const s16x8*)&klds[lrow][kj];
        s16x8 bf = *(const s16x8*)&ulds[lrow][kj];
        acc = __builtin_amdgcn_mfma_f32_16x16x32_bf16(af, bf, acc, 0, 0, 0);
    }
    redc[w][l] = acc;
    __syncthreads();
    if (t < 64) {
        f32x4 sum = redc[0][t] + redc[1][t] + redc[2][t] + redc[3][t];
        int lr = t & 15, kg = t >> 4;
        size_t obase = ((size_t)b * SL + (s0 + kg * 4)) * NH + lr;
#pragma unroll
        for (int r = 0; r < 4; ++r)
            dot[obase + (size_t)r * NH] = sum[r];
        // LSE partial over this block's 16 s, per h=lr
        float m = fmaxf(fmaxf(sum[0], sum[1]), fmaxf(sum[2], sum[3]));
        m = fmaxf(m, __shfl_xor(m, 16));
        m = fmaxf(m, __shfl_xor(m, 32));
        float lsum = __expf(sum[0]-m) + __expf(sum[1]-m) + __expf(sum[2]-m) + __expf(sum[3]-m);
        lsum += __shfl_xor(lsum, 16);
        lsum += __shfl_xor(lsum, 32);
        if (t < 16)
            part[((size_t)b * 128 + st) * 16 + t] = make_float2(m, lsum);
    }
}

// zpart[sq][b][h][j] = sum_{s in tile} dot[b][s][h] * values[s][b][j]
// svpart[sq][b][j]   = sum_{s in tile} values[s][b][j]
// grid 256 = 8 sq x 32 b (b fastest); block 512, thread owns j-pair -> block
// consumes full 4KB values rows (contiguous bursts).
__global__ __launch_bounds__(512) void k_zpart(const float* __restrict__ values,
                                               const float* __restrict__ dotb,
                                               float* __restrict__ zpart,
                                               float* __restrict__ svpart) {
    int b  = blockIdx.x & 31;
    int sq = blockIdx.x >> 5;          // 0..7
    int t  = threadIdx.x;
    __shared__ f32x4 wlds4[1024];      // dot[b][sq*256 ..][16] : 16KB
    {
        const f32x4* src = (const f32x4*)(dotb + ((size_t)b * SL + sq * 256) * NH);
        wlds4[t]       = src[t];
        wlds4[t + 512] = src[t + 512];
    }
    __syncthreads();
    const float* wlds = (const float*)wlds4;

    float ax[NH], ay[NH];
#pragma unroll
    for (int h = 0; h < NH; ++h) { ax[h] = 0.f; ay[h] = 0.f; }
    float svx = 0.f, svy = 0.f;

    const float* vbase = values + ((size_t)(sq * 256) * BSZ + b) * DIM + t * 2;
#pragma unroll 8
    for (int s = 0; s < 256; ++s) {
        float2 v = *(const float2*)(vbase + (size_t)s * (BSZ * DIM));
        const float* wr = wlds + s * 16;
#pragma unroll
        for (int h = 0; h < NH; ++h) {
            float wh = wr[h];
            ax[h] += v.x * wh;
            ay[h] += v.y * wh;
        }
        svx += v.x;
        svy += v.y;
    }
    float* zp = zpart + (size_t)(sq * 32 + b) * NH * DIM + t * 2;
#pragma unroll
    for (int h = 0; h < NH; ++h) {
        float2 o; o.x = ax[h]; o.y = ay[h];
        *(float2*)(zp + (size_t)h * DIM) = o;
    }
    float2 sv; sv.x = svx; sv.y = svy;
    *(float2*)(svpart + (size_t)(sq * 32 + b) * DIM + t * 2) = sv;
}

// attn[b][oc*64+l] = sum_j (sum_p zpart[p][b][oc][j] - T[b][oc]*sum_p svpart[p][b][j]) * Wv[o][j]
// T combined in-prologue from k_dot2 partials (128 per (b,h)).
__global__ __launch_bounds__(256) void k_attn(const float* __restrict__ zpart,
                                              const float* __restrict__ svpart,
                                              const float2* __restrict__ part,
                                              const float* __restrict__ Wv,
                                              float* __restrict__ attn) {
    int oc = blockIdx.x & 15;
    int b  = blockIdx.x >> 4;
    int t  = threadIdx.x;
    int wv = t >> 6, l = t & 63;
    __shared__ float mred[16][16], lred[16][16];
    __shared__ float Tl[16];
    __shared__ float arow[DIM];
    __shared__ float red[4][64];
    {
        int h = t & 15, g = t >> 4;      // 16 groups x 8 parts
        const float2* pb = part + (size_t)b * 128 * 16 + h;
        float M = -1e30f;
        float2 ps[8];
#pragma unroll
        for (int i = 0; i < 8; ++i) ps[i] = pb[(size_t)(g * 8 + i) * 16];
#pragma unroll
        for (int i = 0; i < 8; ++i) M = fmaxf(M, ps[i].x);
        float L = 0.f;
#pragma unroll
        for (int i = 0; i < 8; ++i) L += ps[i].y * __expf(ps[i].x - M);
        mred[g][h] = M; lred[g][h] = L;
    }
    __syncthreads();
    if (t < 16) {
        float M = mred[0][t];
#pragma unroll
        for (int g = 1; g < 16; ++g) M = fmaxf(M, mred[g][t]);
        float L = 0.f;
#pragma unroll
        for (int g = 0; g < 16; ++g) L += lred[g][t] * __expf(mred[g][t] - M);
        Tl[t] = M + __logf(L);
    }
    __syncthreads();
    {
        int k = wv * 256 + l * 4;
        f32x4 a = {0.f,0.f,0.f,0.f}, sv = {0.f,0.f,0.f,0.f};
#pragma unroll
        for (int p = 0; p < 8; ++p) {
            a  += *(const f32x4*)(zpart + ((size_t)((p * 32 + b) * NH + oc)) * DIM + k);
            sv += *(const f32x4*)(svpart + (size_t)(p * 32 + b) * DIM + k);
        }
        a -= Tl[oc] * sv;
        *(f32x4*)&arow[k] = a;
    }
    __syncthreads();
    const float* wr = Wv + (size_t)(oc * 64 + l) * DIM + wv * 256;
    const float* ar = arow + wv * 256;
    f32x4 acc = {0.f,0.f,0.f,0.f};
#pragma unroll 4
    for (int kk = 0; kk < 256; kk += 4)
        acc += *(const f32x4*)(ar + kk) * *(const f32x4*)(wr + kk);
    red[wv][l] = acc[0] + acc[1] + acc[2] + acc[3];
    __syncthreads();
    if (t < 64)
        attn[(size_t)b * DIM + oc * 64 + t] = red[0][t] + red[1][t] + red[2][t] + red[3][t];
}

// out[b][o] = dot(attn[b][:], Wo[o][:])
__global__ __launch_bounds__(256) void k_out(const float* __restrict__ A,
                                             const float* __restrict__ W,
                                             float* __restrict__ O) {
    int oc = blockIdx.x & 15;
    int b  = blockIdx.x >> 4;
    int wv = __builtin_amdgcn_readfirstlane(threadIdx.x >> 6);
    int l  = threadIdx.x & 63;
    int o  = oc * 64 + l;
    const float* arow = A + (size_t)b * DIM + wv * 256;
    const float* wrow = W + (size_t)o * DIM + wv * 256;
    f32x4 acc = {0.f, 0.f, 0.f, 0.f};
#pragma unroll 4
    for (int k = 0; k < 256; k += 4) {
        f32x4 a = *(const f32x4*)(arow + k);
        f32x4 w = *(const f32x4*)(wrow + k);
        acc += a * w;
    }
    __shared__ float red[4][64];
    red[wv][l] = acc[0] + acc[1] + acc[2] + acc[3];
    __syncthreads();
    int t = threadIdx.x;
    if (t < 64)
        O[(size_t)b * DIM + oc * 64 + t] = red[0][t] + red[1][t] + red[2][t] + red[3][t];
}

extern "C" void kernel_launch(void* const* d_in, const int* in_sizes, int n_in,
                              void* d_out, int out_size, void* d_ws, size_t ws_size,
                              hipStream_t stream) {
    const float* query  = (const float*)d_in[0];
    const float* keys   = (const float*)d_in[1];
    const float* values = (const float*)d_in[2];
    const float* Wq = (const float*)d_in[3];
    const float* Wk = (const float*)d_in[4];
    const float* Wv = (const float*)d_in[5];
    const float* Wo = (const float*)d_in[6];
    float* out = (float*)d_out;

    char* ws = (char*)d_ws;
    short*  u      = (short*)(ws + 0);                        // 1 MB
    float*  dotb   = (float*)(ws + (1 << 20));                // 4 MB  [b][s][h]
    float2* part   = (float2*)(ws + (5 << 20));               // 512 KB [b][128][16]
    float*  zpart  = (float*)(ws + (5 << 20) + (512 << 10));  // 16 MB [8][b][h][j]
    float*  svpart = (float*)(ws + (21 << 20) + (512 << 10)); // 1 MB  [8][b][j]
    float*  attn   = (float*)(ws + (22 << 20) + (512 << 10)); // 128 KB

    hipLaunchKernelGGL(k_qu,    dim3(512),  dim3(256), 0, stream, query, Wq, Wk, u);
    hipLaunchKernelGGL(k_dot2,  dim3(4096), dim3(256), 0, stream, keys, u, dotb, part);
    hipLaunchKernelGGL(k_zpart, dim3(256),  dim3(512), 0, stream, values, dotb, zpart, svpart);
    hipLaunchKernelGGL(k_attn,  dim3(512),  dim3(256), 0, stream, zpart, svpart, part, Wv, attn);
    hipLaunchKernelGGL(k_out,   dim3(512),  dim3(256), 0, stream, attn, Wo, out);
}